// Round 1
// baseline (925.151 us; speedup 1.0000x reference)
//
#include <hip/hip_runtime.h>
#include <stdint.h>
#include <stddef.h>

// ---------------------------------------------------------------------------
// time_attention: out = softmax_o(Et*El) * V  -> [N,1024] @ Wo^T + bo
// All heavy math in f16 MFMA (fp32 accumulate). Column mapping c = o*16 + h.
// ---------------------------------------------------------------------------

typedef _Float16 h8 __attribute__((ext_vector_type(8)));
typedef _Float16 h4 __attribute__((ext_vector_type(4)));
typedef float    f4 __attribute__((ext_vector_type(4)));

#define NROWS 32768
#define MULTD 1024

// async global->LDS, 16B per lane (lds dest = wave-uniform base + lane*16)
__device__ __forceinline__ void async_ld16(const void* g, void* s) {
  __builtin_amdgcn_global_load_lds(
      (const __attribute__((address_space(1))) uint32_t*)g,
      (__attribute__((address_space(3))) uint32_t*)s, 16, 0, 0);
}

// ---------------------------------------------------------------------------
// GEMM: C[M x Ncols] = A[M x K (lda)] * B[Ncols x K]^T + bias
// A,B f16; C f16 or f32. Tiles: BM=BN=128, BK=32. 256 threads = 4 waves,
// each wave does a 64x64 subtile = 4x4 MFMA 16x16x32.
// Grid: (M/128, Ncols/128). Dims assumed exact multiples (true here).
// ---------------------------------------------------------------------------
template <bool OUT_F16>
__launch_bounds__(256)
__global__ void gemm_bt(const _Float16* __restrict__ A, int lda,
                        const _Float16* __restrict__ B, int K,
                        const float* __restrict__ bias,
                        void* __restrict__ Cout, int ldc) {
  __shared__ _Float16 As[128 * 32];
  __shared__ _Float16 Bs[128 * 32];

  const int tid  = threadIdx.x;
  const int w    = tid >> 6;       // wave 0..3
  const int lane = tid & 63;
  const int row0 = blockIdx.x * 128;
  const int col0 = blockIdx.y * 128;
  const int wm   = (w >> 1) * 64;  // wave row offset in tile
  const int wn   = (w & 1) * 64;   // wave col offset in tile
  const int lr   = lane >> 2;      // 0..15: row within 16-row slab
  const int lc   = (lane & 3) * 8; // k-chunk (8 halves = 16B)
  const int quad = lane >> 4;      // 0..3
  const int l16  = lane & 15;

  // staging source pointers: wave w stages rows [w*32, w*32+32) of As/Bs
  const _Float16* Ag = A + (size_t)(row0 + w * 32 + lr) * (size_t)lda + lc;
  const _Float16* Bg = B + (size_t)(col0 + w * 32 + lr) * (size_t)K + lc;
  _Float16* AsW = As + w * 1024;   // 32 rows * 32 halves
  _Float16* BsW = Bs + w * 1024;

  f4 acc[4][4];
  const f4 z = {0.f, 0.f, 0.f, 0.f};
#pragma unroll
  for (int i = 0; i < 4; i++)
#pragma unroll
    for (int j = 0; j < 4; j++) acc[i][j] = z;

  for (int k0 = 0; k0 < K; k0 += 32) {
    async_ld16(Ag + k0, AsW);
    async_ld16(Ag + (size_t)16 * lda + k0, AsW + 512);
    async_ld16(Bg + k0, BsW);
    async_ld16(Bg + (size_t)16 * K + k0, BsW + 512);
    __syncthreads();  // drains vmcnt -> LDS tiles complete

    h8 af[4], bf[4];
#pragma unroll
    for (int i = 0; i < 4; i++)
      af[i] = *(const h8*)(As + (wm + i * 16 + l16) * 32 + quad * 8);
#pragma unroll
    for (int j = 0; j < 4; j++)
      bf[j] = *(const h8*)(Bs + (wn + j * 16 + l16) * 32 + quad * 8);

#pragma unroll
    for (int i = 0; i < 4; i++)
#pragma unroll
      for (int j = 0; j < 4; j++)
        acc[i][j] = __builtin_amdgcn_mfma_f32_16x16x32_f16(af[i], bf[j],
                                                           acc[i][j], 0, 0, 0);
    __syncthreads();  // protect LDS before next stage overwrites
  }

  // epilogue: D[(lane>>4)*4 + r][lane&15] per 16x16 subtile
#pragma unroll
  for (int j = 0; j < 4; j++) {
    const int cg = col0 + wn + j * 16 + l16;
    const float bj = bias[cg];
#pragma unroll
    for (int i = 0; i < 4; i++) {
      const int rbase = row0 + wm + i * 16 + quad * 4;
#pragma unroll
      for (int r = 0; r < 4; r++) {
        const float v = acc[i][j][r] + bj;
        if (OUT_F16)
          ((_Float16*)Cout)[(size_t)(rbase + r) * (size_t)ldc + cg] = (_Float16)v;
        else
          ((float*)Cout)[(size_t)(rbase + r) * (size_t)ldc + cg] = v;
      }
    }
  }
}

// ---------------------------------------------------------------------------
// Convert t_inp/lat_inp fp32 -> one f16 buffer X[N][2048] = [t | lat]
// ---------------------------------------------------------------------------
__global__ void cvt_inputs(const float4* __restrict__ t,
                           const float4* __restrict__ l,
                           h4* __restrict__ X) {
  const size_t idx = (size_t)blockIdx.x * 256 + threadIdx.x;  // N*1024/4 total
  const size_t n  = idx >> 8;    // 256 float4 per 1024-row
  const size_t k4 = idx & 255;
  const float4 a = t[idx];
  const float4 b = l[idx];
  h4 ha, hb;
  ha[0] = (_Float16)a.x; ha[1] = (_Float16)a.y;
  ha[2] = (_Float16)a.z; ha[3] = (_Float16)a.w;
  hb[0] = (_Float16)b.x; hb[1] = (_Float16)b.y;
  hb[2] = (_Float16)b.z; hb[3] = (_Float16)b.w;
  X[n * 512 + k4]       = ha;   // row stride 2048 halves = 512 h4
  X[n * 512 + 256 + k4] = hb;
}

// Permute+convert weight: Wp[c][k] = W[h*64+o][k], c = o*16+h. K in {1024,2048}
__global__ void cvt_w_perm(const float* __restrict__ W,
                           _Float16* __restrict__ Wp, int K) {
  const int idx = blockIdx.x * 256 + threadIdx.x;  // 1024*K/4 total
  const int k4s = K >> 2;
  const int c = idx / k4s;
  const int k = (idx - c * k4s) * 4;
  const int h = c & 15, o = c >> 4;
  const float4 v = *(const float4*)(W + (size_t)(h * 64 + o) * (size_t)K + k);
  h4 hv;
  hv[0] = (_Float16)v.x; hv[1] = (_Float16)v.y;
  hv[2] = (_Float16)v.z; hv[3] = (_Float16)v.w;
  *(h4*)(Wp + (size_t)c * (size_t)K + k) = hv;
}

// Flat fp32 -> f16 convert (Wo)
__global__ void cvt_flat(const float4* __restrict__ W, h4* __restrict__ Wp) {
  const int idx = blockIdx.x * 256 + threadIdx.x;
  const float4 v = W[idx];
  h4 hv;
  hv[0] = (_Float16)v.x; hv[1] = (_Float16)v.y;
  hv[2] = (_Float16)v.z; hv[3] = (_Float16)v.w;
  Wp[idx] = hv;
}

// Permute biases: bp[c] = b[h*64+o]
__global__ void cvt_bias3(const float* __restrict__ bt, const float* __restrict__ bl,
                          const float* __restrict__ bv, float* __restrict__ btp,
                          float* __restrict__ blp, float* __restrict__ bvp) {
  const int c = blockIdx.x * 256 + threadIdx.x;  // 1024
  const int src = (c & 15) * 64 + (c >> 4);
  btp[c] = bt[src];
  blp[c] = bl[src];
  bvp[c] = bv[src];
}

// ---------------------------------------------------------------------------
// softmax over o (stride-16 groups of 64) + merge with V. One wave per row:
// lane holds o=lane, h=0..15 (16 contiguous elements). Transpose via LDS for
// the over-o sum, shfl_xor(16/32) to combine 4 partials per h.
// ---------------------------------------------------------------------------
__launch_bounds__(256)
__global__ void softmax_merge(const _Float16* __restrict__ Et,
                              const _Float16* __restrict__ El,
                              const _Float16* __restrict__ V,
                              _Float16* __restrict__ Mg) {
  __shared__ float P[4][64][17];   // [wave][o][h], pad 17 kills column conflicts
  __shared__ float invS[4][16];
  const int w = threadIdx.x >> 6;
  const int lane = threadIdx.x & 63;
  const size_t row = (size_t)blockIdx.x * 4 + w;
  const size_t base = row * 1024 + (size_t)lane * 16;

  const h8 e0 = *(const h8*)(Et + base);
  const h8 e1 = *(const h8*)(Et + base + 8);
  const h8 l0 = *(const h8*)(El + base);
  const h8 l1 = *(const h8*)(El + base + 8);

  float p[16];
#pragma unroll
  for (int h = 0; h < 8; h++) p[h] = __expf((float)e0[h] * (float)l0[h]);
#pragma unroll
  for (int h = 0; h < 8; h++) p[h + 8] = __expf((float)e1[h] * (float)l1[h]);
#pragma unroll
  for (int h = 0; h < 16; h++) P[w][lane][h] = p[h];
  __syncthreads();

  const int hh = lane & 15;
  const int og = (lane >> 4) * 16;
  float s = 0.f;
#pragma unroll
  for (int j = 0; j < 16; j++) s += P[w][og + j][hh];
  s += __shfl_xor(s, 16);
  s += __shfl_xor(s, 32);
  if (lane < 16) invS[w][lane] = 1.0f / s;
  __syncthreads();

  const h8 v0 = *(const h8*)(V + base);
  const h8 v1 = *(const h8*)(V + base + 8);
  h8 m0, m1;
#pragma unroll
  for (int h = 0; h < 8; h++)
    m0[h] = (_Float16)(p[h] * invS[w][h] * (float)v0[h]);
#pragma unroll
  for (int h = 0; h < 8; h++)
    m1[h] = (_Float16)(p[h + 8] * invS[w][h + 8] * (float)v1[h]);
  *(h8*)(Mg + base) = m0;
  *(h8*)(Mg + base + 8) = m1;
}

// ---------------------------------------------------------------------------
// Launch. ws layout (bytes), total 413,151,232 (~394 MB):
//   X16      [N*2048 f16]        134,217,728
//   Wt16p    [1024*1024 f16]       2,097,152
//   Wl16p                          2,097,152
//   Wv16p    [1024*2048 f16]       4,194,304
//   Wo16                           2,097,152
//   btp/blp/bvp [1024 f32 each]       12,288
//   Et16/El16/V16/Mg16 [N*1024 f16] 4 x 67,108,864
// ---------------------------------------------------------------------------
extern "C" void kernel_launch(void* const* d_in, const int* in_sizes, int n_in,
                              void* d_out, int out_size, void* d_ws, size_t ws_size,
                              hipStream_t stream) {
  const float* t_inp = (const float*)d_in[0];
  const float* l_inp = (const float*)d_in[1];
  const float* Wt = (const float*)d_in[2];
  const float* bt = (const float*)d_in[3];
  const float* Wl = (const float*)d_in[4];
  const float* bl = (const float*)d_in[5];
  const float* Wv = (const float*)d_in[6];
  const float* bv = (const float*)d_in[7];
  const float* Wo = (const float*)d_in[8];
  const float* bo = (const float*)d_in[9];
  float* out = (float*)d_out;

  char* ws = (char*)d_ws;
  _Float16* X16  = (_Float16*)ws;
  _Float16* Wt16 = (_Float16*)(ws + 134217728ull);
  _Float16* Wl16 = Wt16 + 1024 * 1024;
  _Float16* Wv16 = Wl16 + 1024 * 1024;
  _Float16* Wo16 = Wv16 + 1024 * 2048;
  float*    btp  = (float*)(Wo16 + 1024 * 1024);
  float*    blp  = btp + 1024;
  float*    bvp  = blp + 1024;
  _Float16* Et   = (_Float16*)(bvp + 1024);
  _Float16* El   = Et + (size_t)NROWS * 1024;
  _Float16* Vv   = El + (size_t)NROWS * 1024;
  _Float16* Mg   = Vv + (size_t)NROWS * 1024;

  // prep
  cvt_inputs<<<dim3(32768), dim3(256), 0, stream>>>(
      (const float4*)t_inp, (const float4*)l_inp, (h4*)X16);
  cvt_w_perm<<<dim3(1024), dim3(256), 0, stream>>>(Wt, Wt16, 1024);
  cvt_w_perm<<<dim3(1024), dim3(256), 0, stream>>>(Wl, Wl16, 1024);
  cvt_w_perm<<<dim3(2048), dim3(256), 0, stream>>>(Wv, Wv16, 2048);
  cvt_flat<<<dim3(1024), dim3(256), 0, stream>>>((const float4*)Wo, (h4*)Wo16);
  cvt_bias3<<<dim3(4), dim3(256), 0, stream>>>(bt, bl, bv, btp, blp, bvp);

  // embed GEMMs (f16 out)
  const dim3 gg(NROWS / 128, MULTD / 128);
  gemm_bt<true><<<gg, dim3(256), 0, stream>>>(X16, 2048, Wt16, 1024, btp, Et, 1024);
  gemm_bt<true><<<gg, dim3(256), 0, stream>>>(X16 + 1024, 2048, Wl16, 1024, blp, El, 1024);
  gemm_bt<true><<<gg, dim3(256), 0, stream>>>(X16, 2048, Wv16, 2048, bvp, Vv, 1024);

  // softmax over o + merge
  softmax_merge<<<dim3(NROWS / 4), dim3(256), 0, stream>>>(Et, El, Vv, Mg);

  // final GEMM (fp32 out)
  gemm_bt<false><<<gg, dim3(256), 0, stream>>>(Mg, 1024, Wo16, 1024, bo, out, 1024);
}

// Round 2
// 877.296 us; speedup vs baseline: 1.0545x; 1.0545x over previous
//
#include <hip/hip_runtime.h>
#include <stdint.h>
#include <stddef.h>

// ---------------------------------------------------------------------------
// Round 2: fused embed+softmax+merge.
// Column order is NATURAL c = h*64+o, so each softmax group (over o) is 64
// contiguous columns = one block's column tile. Et/El/V accumulated together
// (shared A tile); softmax done in-registers via shfl; only Mg hits HBM.
// Final GEMM uses Wo with K-dim permuted (Wo_perm[j][h*64+o] = Wo[j][o*16+h]).
// ---------------------------------------------------------------------------

typedef _Float16 h8 __attribute__((ext_vector_type(8)));
typedef _Float16 h4 __attribute__((ext_vector_type(4)));
typedef float    f4 __attribute__((ext_vector_type(4)));

#define NROWS 32768
#define MULTD 1024

// async global->LDS, 16B per lane (lds dest = wave-uniform base + lane*16)
__device__ __forceinline__ void async_ld16(const void* g, void* s) {
  __builtin_amdgcn_global_load_lds(
      (const __attribute__((address_space(1))) uint32_t*)g,
      (__attribute__((address_space(3))) uint32_t*)s, 16, 0, 0);
}

// ---------------------------------------------------------------------------
// Fused kernel: grid (16 heads, 256 row-blocks), 256 threads = 4 waves.
// Block tile: 128 rows x 64 cols (one head h; cols = o in [0,64)).
// Wave w owns rows [w*32, w*32+32): 2x4 MFMA 16x16x32 per matrix.
// Per K-step: stage A(128x32) shared, B1(Wt or Wl, 64x32), B2(Wv, 64x32).
// ---------------------------------------------------------------------------
__launch_bounds__(256)
__global__ void fused_embed(const _Float16* __restrict__ X,
                            const _Float16* __restrict__ Wt,
                            const _Float16* __restrict__ Wl,
                            const _Float16* __restrict__ Wv,
                            const float* __restrict__ bt,
                            const float* __restrict__ bl,
                            const float* __restrict__ bv,
                            _Float16* __restrict__ Mg) {
  __shared__ _Float16 As[128 * 32];   // 8 KB
  __shared__ _Float16 B1s[64 * 32];   // 4 KB (Wt phase1 / Wl phase2)
  __shared__ _Float16 B2s[64 * 32];   // 4 KB (Wv)
  __shared__ _Float16 MgS[128 * 68];  // 17 KB epilogue staging (pad 68)

  const int h    = blockIdx.x;        // head index 0..15
  const int row0 = blockIdx.y * 128;
  const int tid  = threadIdx.x;
  const int w    = tid >> 6;
  const int lane = tid & 63;
  const int lr   = lane >> 2;         // 0..15
  const int lc   = (lane & 3) * 8;    // k-chunk (8 halves = 16B)
  const int quad = lane >> 4;
  const int l16  = lane & 15;
  const int wm   = w * 32;

  // staging sources
  const _Float16* Ag = X  + (size_t)(row0 + wm + lr) * 2048 + lc;
  const _Float16* Tg = Wt + (size_t)(h * 64 + w * 16 + lr) * 1024 + lc;
  const _Float16* Lg = Wl + (size_t)(h * 64 + w * 16 + lr) * 1024 + lc;
  const _Float16* Vg = Wv + (size_t)(h * 64 + w * 16 + lr) * 2048 + lc;
  _Float16* AsW = As  + wm * 32;       // wave w stages A rows [wm, wm+32)
  _Float16* B1W = B1s + w * 16 * 32;   // rows [w*16, w*16+16)
  _Float16* B2W = B2s + w * 16 * 32;

  f4 acc_t[2][4], acc_l[2][4], acc_v[2][4];
  const f4 z = {0.f, 0.f, 0.f, 0.f};
#pragma unroll
  for (int i = 0; i < 2; i++)
#pragma unroll
    for (int j = 0; j < 4; j++) { acc_t[i][j] = z; acc_l[i][j] = z; acc_v[i][j] = z; }

  // ---- phase 1: k in [0,1024): Et (Wt) + V ----
  for (int k0 = 0; k0 < 1024; k0 += 32) {
    async_ld16(Ag + k0, AsW);
    async_ld16(Ag + (size_t)16 * 2048 + k0, AsW + 512);
    async_ld16(Tg + k0, B1W);
    async_ld16(Vg + k0, B2W);
    __syncthreads();

    h8 af[2], b1[4], b2[4];
#pragma unroll
    for (int i = 0; i < 2; i++)
      af[i] = *(const h8*)(As + (wm + i * 16 + l16) * 32 + quad * 8);
#pragma unroll
    for (int j = 0; j < 4; j++) {
      b1[j] = *(const h8*)(B1s + (j * 16 + l16) * 32 + quad * 8);
      b2[j] = *(const h8*)(B2s + (j * 16 + l16) * 32 + quad * 8);
    }
#pragma unroll
    for (int i = 0; i < 2; i++)
#pragma unroll
      for (int j = 0; j < 4; j++) {
        acc_t[i][j] = __builtin_amdgcn_mfma_f32_16x16x32_f16(af[i], b1[j], acc_t[i][j], 0, 0, 0);
        acc_v[i][j] = __builtin_amdgcn_mfma_f32_16x16x32_f16(af[i], b2[j], acc_v[i][j], 0, 0, 0);
      }
    __syncthreads();
  }

  // ---- phase 2: k in [1024,2048): El (Wl) + V ----
  for (int k0 = 0; k0 < 1024; k0 += 32) {
    async_ld16(Ag + 1024 + k0, AsW);
    async_ld16(Ag + (size_t)16 * 2048 + 1024 + k0, AsW + 512);
    async_ld16(Lg + k0, B1W);
    async_ld16(Vg + 1024 + k0, B2W);
    __syncthreads();

    h8 af[2], b1[4], b2[4];
#pragma unroll
    for (int i = 0; i < 2; i++)
      af[i] = *(const h8*)(As + (wm + i * 16 + l16) * 32 + quad * 8);
#pragma unroll
    for (int j = 0; j < 4; j++) {
      b1[j] = *(const h8*)(B1s + (j * 16 + l16) * 32 + quad * 8);
      b2[j] = *(const h8*)(B2s + (j * 16 + l16) * 32 + quad * 8);
    }
#pragma unroll
    for (int i = 0; i < 2; i++)
#pragma unroll
      for (int j = 0; j < 4; j++) {
        acc_l[i][j] = __builtin_amdgcn_mfma_f32_16x16x32_f16(af[i], b1[j], acc_l[i][j], 0, 0, 0);
        acc_v[i][j] = __builtin_amdgcn_mfma_f32_16x16x32_f16(af[i], b2[j], acc_v[i][j], 0, 0, 0);
      }
    __syncthreads();
  }

  // ---- epilogue: bias, p=exp(t*l), row-sum over 64 cols (in-wave), merge ----
#pragma unroll
  for (int i = 0; i < 2; i++) {
    float pv[4][4];
    float s[4] = {0.f, 0.f, 0.f, 0.f};
#pragma unroll
    for (int j = 0; j < 4; j++) {
      const int cg = h * 64 + j * 16 + l16;
      const float btj = bt[cg], blj = bl[cg], bvj = bv[cg];
#pragma unroll
      for (int r = 0; r < 4; r++) {
        const float tv = acc_t[i][j][r] + btj;
        const float lv = acc_l[i][j][r] + blj;
        const float vv = acc_v[i][j][r] + bvj;
        const float p  = __expf(tv * lv);
        pv[j][r] = p * vv;
        s[r] += p;
      }
    }
#pragma unroll
    for (int r = 0; r < 4; r++) {
      s[r] += __shfl_xor(s[r], 1);
      s[r] += __shfl_xor(s[r], 2);
      s[r] += __shfl_xor(s[r], 4);
      s[r] += __shfl_xor(s[r], 8);
      s[r] = 1.0f / s[r];
    }
#pragma unroll
    for (int j = 0; j < 4; j++)
#pragma unroll
      for (int r = 0; r < 4; r++)
        MgS[(wm + i * 16 + quad * 4 + r) * 68 + j * 16 + l16] =
            (_Float16)(pv[j][r] * s[r]);
  }
  __syncthreads();

  // coalesced tile store: 128 rows x 64 cols at (row0, h*64)
  for (int cc = tid; cc < 1024; cc += 256) {
    const int row = cc >> 3, ch = cc & 7;
    *(h8*)(Mg + (size_t)(row0 + row) * 1024 + h * 64 + ch * 8) =
        *(const h8*)(MgS + row * 68 + ch * 8);
  }
}

// ---------------------------------------------------------------------------
// GEMM (final projection): C[M x N] = A[M x K] * B[N x K]^T + bias, fp32 out.
// Same structure as round 1.
// ---------------------------------------------------------------------------
__launch_bounds__(256)
__global__ void gemm_bt(const _Float16* __restrict__ A, int lda,
                        const _Float16* __restrict__ B, int K,
                        const float* __restrict__ bias,
                        float* __restrict__ Cout, int ldc) {
  __shared__ _Float16 As[128 * 32];
  __shared__ _Float16 Bs[128 * 32];

  const int tid  = threadIdx.x;
  const int w    = tid >> 6;
  const int lane = tid & 63;
  const int row0 = blockIdx.x * 128;
  const int col0 = blockIdx.y * 128;
  const int wm   = (w >> 1) * 64;
  const int wn   = (w & 1) * 64;
  const int lr   = lane >> 2;
  const int lc   = (lane & 3) * 8;
  const int quad = lane >> 4;
  const int l16  = lane & 15;

  const _Float16* Ag = A + (size_t)(row0 + w * 32 + lr) * (size_t)lda + lc;
  const _Float16* Bg = B + (size_t)(col0 + w * 32 + lr) * (size_t)K + lc;
  _Float16* AsW = As + w * 1024;
  _Float16* BsW = Bs + w * 1024;

  f4 acc[4][4];
  const f4 z = {0.f, 0.f, 0.f, 0.f};
#pragma unroll
  for (int i = 0; i < 4; i++)
#pragma unroll
    for (int j = 0; j < 4; j++) acc[i][j] = z;

  for (int k0 = 0; k0 < K; k0 += 32) {
    async_ld16(Ag + k0, AsW);
    async_ld16(Ag + (size_t)16 * lda + k0, AsW + 512);
    async_ld16(Bg + k0, BsW);
    async_ld16(Bg + (size_t)16 * K + k0, BsW + 512);
    __syncthreads();

    h8 af[4], bf[4];
#pragma unroll
    for (int i = 0; i < 4; i++)
      af[i] = *(const h8*)(As + (wm + i * 16 + l16) * 32 + quad * 8);
#pragma unroll
    for (int j = 0; j < 4; j++)
      bf[j] = *(const h8*)(Bs + (wn + j * 16 + l16) * 32 + quad * 8);

#pragma unroll
    for (int i = 0; i < 4; i++)
#pragma unroll
      for (int j = 0; j < 4; j++)
        acc[i][j] = __builtin_amdgcn_mfma_f32_16x16x32_f16(af[i], bf[j],
                                                           acc[i][j], 0, 0, 0);
    __syncthreads();
  }

#pragma unroll
  for (int j = 0; j < 4; j++) {
    const int cg = col0 + wn + j * 16 + l16;
    const float bj = bias[cg];
#pragma unroll
    for (int i = 0; i < 4; i++) {
      const int rbase = row0 + wm + i * 16 + quad * 4;
#pragma unroll
      for (int r = 0; r < 4; r++)
        Cout[(size_t)(rbase + r) * (size_t)ldc + cg] = acc[i][j][r] + bj;
    }
  }
}

// ---------------------------------------------------------------------------
// Prep kernels
// ---------------------------------------------------------------------------
__global__ void cvt_inputs(const float4* __restrict__ t,
                           const float4* __restrict__ l,
                           h4* __restrict__ X) {
  const size_t idx = (size_t)blockIdx.x * 256 + threadIdx.x;  // N*1024/4
  const size_t n  = idx >> 8;
  const size_t k4 = idx & 255;
  const float4 a = t[idx];
  const float4 b = l[idx];
  h4 ha, hb;
  ha[0] = (_Float16)a.x; ha[1] = (_Float16)a.y;
  ha[2] = (_Float16)a.z; ha[3] = (_Float16)a.w;
  hb[0] = (_Float16)b.x; hb[1] = (_Float16)b.y;
  hb[2] = (_Float16)b.z; hb[3] = (_Float16)b.w;
  X[n * 512 + k4]       = ha;
  X[n * 512 + 256 + k4] = hb;
}

// flat fp32 -> f16 (Wt, Wl, Wv: natural layout, no permute needed)
__global__ void cvt_flat(const float4* __restrict__ W, h4* __restrict__ Wp) {
  const int idx = blockIdx.x * 256 + threadIdx.x;
  const float4 v = W[idx];
  h4 hv;
  hv[0] = (_Float16)v.x; hv[1] = (_Float16)v.y;
  hv[2] = (_Float16)v.z; hv[3] = (_Float16)v.w;
  Wp[idx] = hv;
}

// Wo with K-dim permuted: Wp[j][c=h*64+o] = Wo[j][o*16+h]
__global__ void cvt_wo_perm(const float* __restrict__ Wo,
                            _Float16* __restrict__ Wp) {
  const int idx = blockIdx.x * 256 + threadIdx.x;  // 1M
  const int j = idx >> 10, c = idx & 1023;
  const int k = (c & 63) * 16 + (c >> 6);
  Wp[idx] = (_Float16)Wo[j * 1024 + k];
}

// ---------------------------------------------------------------------------
// Launch. ws layout (bytes), total ~208 MB:
//   X16   [N*2048 f16]   134,217,728
//   Wt16  [1024*1024]      2,097,152
//   Wl16                   2,097,152
//   Wv16  [1024*2048]      4,194,304
//   Wo16p [1024*1024]      2,097,152
//   Mg    [N*1024 f16]    67,108,864
// ---------------------------------------------------------------------------
extern "C" void kernel_launch(void* const* d_in, const int* in_sizes, int n_in,
                              void* d_out, int out_size, void* d_ws, size_t ws_size,
                              hipStream_t stream) {
  const float* t_inp = (const float*)d_in[0];
  const float* l_inp = (const float*)d_in[1];
  const float* Wt = (const float*)d_in[2];
  const float* bt = (const float*)d_in[3];
  const float* Wl = (const float*)d_in[4];
  const float* bl = (const float*)d_in[5];
  const float* Wv = (const float*)d_in[6];
  const float* bv = (const float*)d_in[7];
  const float* Wo = (const float*)d_in[8];
  const float* bo = (const float*)d_in[9];
  float* out = (float*)d_out;

  char* ws = (char*)d_ws;
  _Float16* X16  = (_Float16*)ws;
  _Float16* Wt16 = (_Float16*)(ws + 134217728ull);
  _Float16* Wl16 = Wt16 + 1024 * 1024;
  _Float16* Wv16 = Wl16 + 1024 * 1024;
  _Float16* Wo16 = Wv16 + 1024 * 2048;
  _Float16* Mg   = Wo16 + 1024 * 1024;

  cvt_inputs<<<dim3(32768), dim3(256), 0, stream>>>(
      (const float4*)t_inp, (const float4*)l_inp, (h4*)X16);
  cvt_flat<<<dim3(1024), dim3(256), 0, stream>>>((const float4*)Wt, (h4*)Wt16);
  cvt_flat<<<dim3(1024), dim3(256), 0, stream>>>((const float4*)Wl, (h4*)Wl16);
  cvt_flat<<<dim3(2048), dim3(256), 0, stream>>>((const float4*)Wv, (h4*)Wv16);
  cvt_wo_perm<<<dim3(4096), dim3(256), 0, stream>>>(Wo, Wo16);

  // fused embed + softmax + merge -> Mg
  fused_embed<<<dim3(16, NROWS / 128), dim3(256), 0, stream>>>(
      X16, Wt16, Wl16, Wv16, bt, bl, bv, Mg);

  // final projection (fp32 out)
  gemm_bt<<<dim3(NROWS / 128, MULTD / 128), dim3(256), 0, stream>>>(
      Mg, 1024, Wo16, 1024, bo, out, 1024);
}